// Round 1
// baseline (404.760 us; speedup 1.0000x reference)
//
#include <hip/hip_runtime.h>

#define TT 1024
#define NB 4096
#define HH 50
#define DTC 0.1f
#define NL2E2 -2.8853900817779268f      // -2*log2(e)
#define INVNL2E2 -0.34657359027997264f  // 1/NL2E2 = -ln2/2

typedef __attribute__((ext_vector_type(8))) short short8;
typedef __attribute__((ext_vector_type(4))) float float4v;
typedef __attribute__((ext_vector_type(4))) unsigned int uint4v;

__device__ __forceinline__ unsigned short f2bf(float f) {
    unsigned int u = __builtin_bit_cast(unsigned int, f);
    u += 0x7FFFu + ((u >> 16) & 1u);   // RNE
    return (unsigned short)(u >> 16);
}

// Augmented matrix (dt and the sigmoid 1/2 folded in, PLUS the NL2E2 = -2*log2(e)
// state pre-scale folded into every row so exp2() applies directly to the state):
//   rows 0..49:  [0.2*Jrec | 0.1*bias | 0.1*Jin | 0] * NL2E2
//   row  50:     [0.2*Jout@Jrec | 0.1*Jout@bias | 0.1*Jout@Jin | 0] * NL2E2
// State hs = NL2E2 * h;  hs_next = 0.9*hs + A' @ r',  r' = sigmoid(2h) = rcp(1+exp2(hs)).
// B slots: rows 0..49 = r', row 50 = 1, row 51 = x_t, rows 52..63 = don't-care (A cols zero).
//
// SINGLE-WAVE-AUTONOMOUS layout: one wave owns all 64 rows x 16 batch cols.
// C-layout: lane (n = lane&15, q = lane>>4) holds rows {16m + 4q + r} for col n.
// B-frag f, slot j for lane (n,q) is chosen as row rho(q,j,f) = 32f + 16*(j>>2) + 4q + (j&3)
// -- exactly the rows the lane already holds, so NO cross-lane/LDS traffic per step.
// A is pre-permuted by the setup kernel with the same rho (rho is a function of s=8q+j
// alone, so the A/B slot-permutation cancellation verified in the previous kernel holds).
// A_perm layout: [(m*2+f)][lane][8 shorts]  -> 8 coalesced short8 loads per wave.
__global__ void setup_kernel(const float* __restrict__ Jin,
                             const float* __restrict__ Jrec,
                             const float* __restrict__ Jout,
                             const float* __restrict__ bias,
                             const float* __restrict__ h0,
                             float* __restrict__ out0,
                             unsigned short* __restrict__ Aperm) {
    const int tid = threadIdx.x;
    const int blk = blockIdx.x;
    if (blk < 16) {
        const int col = blk * 256 + tid;
        float s = 0.f;
        for (int i = 0; i < HH; ++i) s += Jout[i] * h0[i * NB + col];
        out0[col] = s;
    } else {
        for (int idx = tid; idx < 8 * 64 * 8; idx += 256) {
            const int p = idx >> 9;          // m*2 + f
            const int l = (idx >> 3) & 63;   // lane
            const int j = idx & 7;           // slot
            const int m = p >> 1, f = p & 1;
            const int i = l & 15, q = l >> 4;
            const int row = 16 * m + i;
            const int k = 32 * f + 16 * (j >> 2) + 4 * q + (j & 3);
            float v = 0.f;
            if (row < HH) {
                if (k < HH)           v = 2.0f * DTC * Jrec[row * HH + k];
                else if (k == HH)     v = DTC * bias[row];
                else if (k == HH + 1) v = DTC * Jin[row];
            } else if (row == HH) {
                if (k < HH) {
                    float s = 0.f;
                    for (int i2 = 0; i2 < HH; ++i2) s += Jout[i2] * Jrec[i2 * HH + k];
                    v = 2.0f * DTC * s;
                } else if (k == HH) {
                    float s = 0.f;
                    for (int i2 = 0; i2 < HH; ++i2) s += Jout[i2] * bias[i2];
                    v = DTC * s;
                } else if (k == HH + 1) {
                    float s = 0.f;
                    for (int i2 = 0; i2 < HH; ++i2) s += Jout[i2] * Jin[i2];
                    v = DTC * s;
                }
            }
            Aperm[idx] = f2bf(NL2E2 * v);
        }
    }
}

// sigmoid + bf16 pack into the two B fragments.
// Tile 3 regs r=2,3 are the const-1 and x slots for q==0 (and hit all-zero A
// columns for q>=1), so they never need a sigmoid and need NO divergent branch.
__device__ __forceinline__ void sigpack(const float (&hs)[4][4], float xcur,
                                        short8& b0, short8& b1) {
    unsigned int u[4][4];
#pragma unroll
    for (int m = 0; m < 3; ++m)
#pragma unroll
        for (int r = 0; r < 4; ++r) {
            float e = __builtin_amdgcn_exp2f(hs[m][r]);
            float rv = __builtin_amdgcn_rcpf(1.0f + e);
            u[m][r] = __builtin_bit_cast(unsigned int, rv) + 0x8000u;  // round-half-up
        }
    {
        float e0 = __builtin_amdgcn_exp2f(hs[3][0]);
        u[3][0] = __builtin_bit_cast(unsigned int, __builtin_amdgcn_rcpf(1.0f + e0)) + 0x8000u;
        float e1 = __builtin_amdgcn_exp2f(hs[3][1]);
        u[3][1] = __builtin_bit_cast(unsigned int, __builtin_amdgcn_rcpf(1.0f + e1)) + 0x8000u;
        u[3][2] = 0x3F800000u + 0x8000u;                               // 1.0
        u[3][3] = __builtin_bit_cast(unsigned int, xcur) + 0x8000u;    // x_t
    }
    uint4v p0, p1;
    p0[0] = __builtin_amdgcn_perm(u[0][1], u[0][0], 0x07060302u);
    p0[1] = __builtin_amdgcn_perm(u[0][3], u[0][2], 0x07060302u);
    p0[2] = __builtin_amdgcn_perm(u[1][1], u[1][0], 0x07060302u);
    p0[3] = __builtin_amdgcn_perm(u[1][3], u[1][2], 0x07060302u);
    p1[0] = __builtin_amdgcn_perm(u[2][1], u[2][0], 0x07060302u);
    p1[1] = __builtin_amdgcn_perm(u[2][3], u[2][2], 0x07060302u);
    p1[2] = __builtin_amdgcn_perm(u[3][1], u[3][0], 0x07060302u);
    p1[3] = __builtin_amdgcn_perm(u[3][3], u[3][2], 0x07060302u);
    b0 = __builtin_bit_cast(short8, p0);
    b1 = __builtin_bit_cast(short8, p1);
}

// 256 blocks x 64 threads: ONE wave per CU owns 16 batch cols and the full 64-row
// state. No LDS, no barriers -- the whole T=1024 recurrence stays in registers.
__global__ void __launch_bounds__(64) rnn_kernel(
        const float* __restrict__ x,
        const float* __restrict__ h0,
        const float* __restrict__ out0,
        const unsigned short* __restrict__ Aperm,
        float* __restrict__ out) {
    const int lane = threadIdx.x & 63;
    const int n    = lane & 15;
    const int q    = lane >> 4;
    const int col  = (blockIdx.x << 4) + n;

    // A fragments: 4 M-tiles x 2 K-frags, pre-permuted; 8 coalesced 16B loads.
    short8 a[4][2];
#pragma unroll
    for (int m = 0; m < 4; ++m)
#pragma unroll
        for (int f = 0; f < 2; ++f)
            a[m][f] = *(const short8*)(Aperm + ((((m << 1) + f) << 9) + (lane << 3)));

    // state hs = NL2E2 * h; hs[m][r] holds row 16m + 4q + r for column col
    float hs[4][4];
#pragma unroll
    for (int m = 0; m < 4; ++m)
#pragma unroll
        for (int r = 0; r < 4; ++r) {
            const int row = (m << 4) + (q << 2) + r;
            hs[m][r] = (row < HH) ? NL2E2 * h0[row * NB + col] : 0.f;
        }
    if (q == 0) hs[3][2] = NL2E2 * out0[col];   // row 50 = running out, pre-scaled

    const float* xp = x + col;
    float* outp = out + col;

    // x prefetch chain, depth 3 (~1100 cy cover vs ~900 cy HBM cold miss)
    float x0  = xp[0];
    float xn1 = xp[NB];
    float xn2 = xp[2 * NB];

    short8 b0, b1;
    sigpack(hs, x0, b0, b1);   // r'(h0) + {1, x_0}

#pragma unroll 2
    for (int t = 0; t < TT; ++t) {
        // prefetch x_{t+3}
        const int tt = (t + 3 < TT) ? t + 3 : TT - 1;
        float xf = xp[tt * NB];

        float4v acc[4];
#pragma unroll
        for (int m = 0; m < 4; ++m) {
            float4v z = {0.f, 0.f, 0.f, 0.f};
            z = __builtin_amdgcn_mfma_f32_16x16x32_bf16(a[m][0], b0, z, 0, 0, 0);
            z = __builtin_amdgcn_mfma_f32_16x16x32_bf16(a[m][1], b1, z, 0, 0, 0);
            acc[m] = z;
        }
#pragma unroll
        for (int m = 0; m < 4; ++m)
#pragma unroll
            for (int r = 0; r < 4; ++r)
                hs[m][r] = __builtin_fmaf(hs[m][r], 1.0f - DTC, acc[m][r]);

        if (q == 0) outp[t * NB] = hs[3][2] * INVNL2E2;   // out_t (un-scale)

        sigpack(hs, xn1, b0, b1);   // B for step t+1 (uses x_{t+1})

        xn1 = xn2; xn2 = xf;
    }
}

extern "C" void kernel_launch(void* const* d_in, const int* in_sizes, int n_in,
                              void* d_out, int out_size, void* d_ws, size_t ws_size,
                              hipStream_t stream) {
    (void)in_sizes; (void)n_in; (void)out_size; (void)ws_size;
    const float* x    = (const float*)d_in[0];
    const float* Jin  = (const float*)d_in[1];
    const float* Jrec = (const float*)d_in[2];
    const float* Jout = (const float*)d_in[3];
    const float* bias = (const float*)d_in[4];
    const float* h0   = (const float*)d_in[5];
    float* out = (float*)d_out;

    float* ws_out0 = (float*)d_ws;                            // 4096 f32
    unsigned short* ws_A = (unsigned short*)(ws_out0 + NB);   // 4096 bf16 (permuted)

    hipLaunchKernelGGL(setup_kernel, dim3(17), dim3(256), 0, stream,
                       Jin, Jrec, Jout, bias, h0, ws_out0, ws_A);
    hipLaunchKernelGGL(rnn_kernel, dim3(NB / 16), dim3(64), 0, stream,
                       x, h0, ws_out0, ws_A, out);
}

// Round 2
// 368.999 us; speedup vs baseline: 1.0969x; 1.0969x over previous
//
#include <hip/hip_runtime.h>

#define TT 1024
#define NB 4096
#define HH 50
#define DTC 0.1f
#define NL2E2 -2.8853900817779268f      // -2*log2(e)
#define INVNL2E2 -0.34657359027997264f  // 1/NL2E2 = -ln2/2

typedef __attribute__((ext_vector_type(8))) short short8;
typedef __attribute__((ext_vector_type(4))) float float4v;
typedef __attribute__((ext_vector_type(4))) unsigned int uint4v;

__device__ __forceinline__ unsigned short f2bf(float f) {
    unsigned int u = __builtin_bit_cast(unsigned int, f);
    u += 0x7FFFu + ((u >> 16) & 1u);   // RNE
    return (unsigned short)(u >> 16);
}

// ---------------------------------------------------------------------------
// State layout: 64 physical slots p = 32w | 16t | 4q | r.
// Wave w owns slots 32w..32w+31 (= B-fragment w); lane (n,q) holds reg hs[t][r]
// = slot 32w+16t+4q+r for batch column n.  Logical rows are PERMUTED onto the
// physical slots so every (w,q) lane group has <=7 sigmoid slots (load balance):
//   wave0: q0 rows 0-6, q1 7-12, q2 13-18, q3 19-24
//   wave1: q0 rows 25-29 + out(50) + x(51), q1 30-36, q2 37-43, q3 44-49
// Within a group, slot order s = 4t+r: s<cnt real, then specials, s=7 always dead.
// A' = P * Aaug * P^T; the MFMA k-slot mapping sigma(q,j,f)=32f+16(j>>2)+4q+(j&3)
// is applied identically to A and B (cancellation verified on HW in round 1).
// ---------------------------------------------------------------------------
__device__ __forceinline__ int slot2logical(int p) {
    const int g = ((p >> 3) & 4) | ((p >> 2) & 3);   // 4w + q
    const int s = ((p >> 2) & 4) | (p & 3);          // 4t + r
    const int base[8] = {0, 7, 13, 19, 25, 30, 37, 44};
    const int cnt [8] = {7, 6, 6, 6, 5, 7, 7, 6};
    if (s < cnt[g]) return base[g] + s;
    if (g == 4 && s == 5) return 50;   // out
    if (g == 4 && s == 6) return 51;   // x
    return -1;                          // dead
}

// Augmented matrix (dt, sigmoid-1/2, and the NL2E2 state pre-scale folded in):
//   rows 0..49:  [0.2*Jrec | 0.1*bias | 0.1*Jin | 0] * NL2E2
//   row  50:     [0.2*Jout@Jrec | 0.1*Jout@bias | 0.1*Jout@Jin | 0] * NL2E2
// hs_next = 0.9*hs + A' @ r',  r' = rcp(1 + exp2(hs));  B: out-slot=1, x-slot=x_t.
__global__ void setup_kernel(const float* __restrict__ Jin,
                             const float* __restrict__ Jrec,
                             const float* __restrict__ Jout,
                             const float* __restrict__ bias,
                             const float* __restrict__ h0,
                             float* __restrict__ out0,
                             unsigned short* __restrict__ Aperm) {
    const int tid = threadIdx.x;
    const int blk = blockIdx.x;
    if (blk < 16) {
        const int col = blk * 256 + tid;
        float s = 0.f;
        for (int i = 0; i < HH; ++i) s += Jout[i] * h0[i * NB + col];
        out0[col] = s;
    } else {
        // Aperm layout: [w][t][f][lane][j] : idx = (w<<11)|(t<<10)|(f<<9)|(lane<<3)|j
        for (int idx = tid; idx < 4096; idx += 256) {
            const int j    = idx & 7;
            const int lane = (idx >> 3) & 63;
            const int f    = (idx >> 9) & 1;
            const int t    = (idx >> 10) & 1;
            const int w    = (idx >> 11) & 1;
            const int n = lane & 15, q = lane >> 4;
            const int row_p = 16 * (2 * w + t) + n;
            const int col_p = 32 * f + 16 * (j >> 2) + 4 * q + (j & 3);
            const int Lr = slot2logical(row_p);
            const int Lc = slot2logical(col_p);
            float v = 0.f;
            if (Lr >= 0 && Lc >= 0 && Lr <= HH && Lc <= HH + 1) {
                if (Lr < HH) {
                    if (Lc < HH)           v = 2.0f * DTC * Jrec[Lr * HH + Lc];
                    else if (Lc == HH)     v = DTC * bias[Lr];
                    else if (Lc == HH + 1) v = DTC * Jin[Lr];
                } else if (Lr == HH) {
                    if (Lc < HH) {
                        float s = 0.f;
                        for (int i = 0; i < HH; ++i) s += Jout[i] * Jrec[i * HH + Lc];
                        v = 2.0f * DTC * s;
                    } else if (Lc == HH) {
                        float s = 0.f;
                        for (int i = 0; i < HH; ++i) s += Jout[i] * bias[i];
                        v = DTC * s;
                    } else if (Lc == HH + 1) {
                        float s = 0.f;
                        for (int i = 0; i < HH; ++i) s += Jout[i] * Jin[i];
                        v = DTC * s;
                    }
                }
                // Lr == 51 (x row): stays 0 -> x state never fed back
            }
            Aperm[idx] = f2bf(NL2E2 * v);
        }
    }
}

// Order LDS only; leave global loads/stores in flight.
#define BAR() __asm__ volatile("s_waitcnt lgkmcnt(0)\n\ts_barrier" ::: "memory")

// 256 blocks x 128 threads (2 waves).  Each block = 16 batch cols; wave w owns
// fragment w of the state.  Per step: 4 MFMA + 7 sigmoid pairs per wave, one
// 16B/lane LDS fragment exchange, one barrier.
__global__ void __launch_bounds__(128) rnn_kernel(
        const float* __restrict__ x,
        const float* __restrict__ h0,
        const float* __restrict__ out0,
        const unsigned short* __restrict__ Aperm,
        float* __restrict__ out) {
    __shared__ unsigned short xbuf[2][2][64][8];   // [buf][frag][lane][8] = 4KB

    const int tid  = threadIdx.x;
    const int w    = tid >> 6;
    const int lane = tid & 63;
    const int n    = lane & 15;
    const int q    = lane >> 4;
    const int col  = (blockIdx.x << 4) + n;
    const int wo   = w ^ 1;

    // A fragments in NAMED registers (no runtime-indexed reg arrays -> no scratch)
    const short8 a0_own = *(const short8*)(Aperm + ((w << 11) | (0 << 10) | (w  << 9) | (lane << 3)));
    const short8 a0_oth = *(const short8*)(Aperm + ((w << 11) | (0 << 10) | (wo << 9) | (lane << 3)));
    const short8 a1_own = *(const short8*)(Aperm + ((w << 11) | (1 << 10) | (w  << 9) | (lane << 3)));
    const short8 a1_oth = *(const short8*)(Aperm + ((w << 11) | (1 << 10) | (wo << 9) | (lane << 3)));

    // state init (permuted h0 load; off the hot loop)
    float hs[2][4];
#pragma unroll
    for (int t = 0; t < 2; ++t)
#pragma unroll
        for (int r = 0; r < 4; ++r) {
            const int p = (w << 5) | (t << 4) | (q << 2) | r;
            const int L = slot2logical(p);
            float v = 0.f;
            if (L >= 0 && L < HH)      v = NL2E2 * h0[L * NB + col];
            else if (L == HH)          v = NL2E2 * out0[col];
            hs[t][r] = v;
        }

    const bool sp = (w == 1) && (q == 0);   // lane group holding out(t1,r1) and x(t1,r2)
    const float* xp = x + col;
    float* outp = out + col;

    // x prefetch chain, depth 3
    float x0  = xp[0];
    float xn1 = xp[NB];
    float xn2 = xp[2 * NB];

    short8 b_own;
    {   // prologue: r'(h0) for own fragment
        unsigned int u[2][4];
#pragma unroll
        for (int t = 0; t < 2; ++t)
#pragma unroll
            for (int r = 0; r < 4; ++r) {
                if (t == 1 && r == 3) { u[1][3] = 0u; continue; }  // always dead
                float e = __builtin_amdgcn_exp2f(hs[t][r]);
                u[t][r] = __builtin_bit_cast(unsigned int, __builtin_amdgcn_rcpf(1.0f + e));
            }
        if (sp) { u[1][1] = 0x3F800000u; u[1][2] = __builtin_bit_cast(unsigned int, x0); }
#pragma unroll
        for (int t = 0; t < 2; ++t)
#pragma unroll
            for (int r = 0; r < 4; ++r) u[t][r] += 0x8000u;        // round-half-up
        uint4v pk;
        pk[0] = __builtin_amdgcn_perm(u[0][1], u[0][0], 0x07060302u);
        pk[1] = __builtin_amdgcn_perm(u[0][3], u[0][2], 0x07060302u);
        pk[2] = __builtin_amdgcn_perm(u[1][1], u[1][0], 0x07060302u);
        pk[3] = __builtin_amdgcn_perm(u[1][3], u[1][2], 0x07060302u);
        b_own = __builtin_bit_cast(short8, pk);
        *(uint4v*)&xbuf[0][w][lane][0] = pk;
    }
    BAR();

#pragma unroll 2
    for (int t = 0; t < TT; ++t) {
        const int buf = t & 1;
        // other wave's fragment: issue the read FIRST (latency hidden under own MFMAs)
        short8 b_oth = *(const short8*)&xbuf[buf][wo][lane][0];

        // prefetch x_{t+3}
        const int tt3 = (t + 3 < TT) ? t + 3 : TT - 1;
        float xf = xp[tt3 * NB];

        float4v z0 = {0.f, 0.f, 0.f, 0.f};
        float4v z1 = {0.f, 0.f, 0.f, 0.f};
        z0 = __builtin_amdgcn_mfma_f32_16x16x32_bf16(a0_own, b_own, z0, 0, 0, 0);
        z1 = __builtin_amdgcn_mfma_f32_16x16x32_bf16(a1_own, b_own, z1, 0, 0, 0);
        z0 = __builtin_amdgcn_mfma_f32_16x16x32_bf16(a0_oth, b_oth, z0, 0, 0, 0);
        z1 = __builtin_amdgcn_mfma_f32_16x16x32_bf16(a1_oth, b_oth, z1, 0, 0, 0);

#pragma unroll
        for (int r = 0; r < 4; ++r) hs[0][r] = __builtin_fmaf(hs[0][r], 1.0f - DTC, z0[r]);
#pragma unroll
        for (int r = 0; r < 4; ++r) hs[1][r] = __builtin_fmaf(hs[1][r], 1.0f - DTC, z1[r]);

        // r' for step t+1 (7 sigmoid pairs; specials overwrite; slot t1r3 dead)
        unsigned int u[2][4];
#pragma unroll
        for (int tt2 = 0; tt2 < 2; ++tt2)
#pragma unroll
            for (int r = 0; r < 4; ++r) {
                if (tt2 == 1 && r == 3) { u[1][3] = 0u; continue; }
                float e = __builtin_amdgcn_exp2f(hs[tt2][r]);
                u[tt2][r] = __builtin_bit_cast(unsigned int, __builtin_amdgcn_rcpf(1.0f + e));
            }
        if (sp) { u[1][1] = 0x3F800000u; u[1][2] = __builtin_bit_cast(unsigned int, xn1); }
#pragma unroll
        for (int tt2 = 0; tt2 < 2; ++tt2)
#pragma unroll
            for (int r = 0; r < 4; ++r) u[tt2][r] += 0x8000u;
        uint4v pk;
        pk[0] = __builtin_amdgcn_perm(u[0][1], u[0][0], 0x07060302u);
        pk[1] = __builtin_amdgcn_perm(u[0][3], u[0][2], 0x07060302u);
        pk[2] = __builtin_amdgcn_perm(u[1][1], u[1][0], 0x07060302u);
        pk[3] = __builtin_amdgcn_perm(u[1][3], u[1][2], 0x07060302u);
        b_own = __builtin_bit_cast(short8, pk);
        *(uint4v*)&xbuf[buf ^ 1][w][lane][0] = pk;

        if (sp) outp[t * NB] = hs[1][1] * INVNL2E2;   // out_t (un-scale), off barrier path

        xn1 = xn2; xn2 = xf;
        BAR();
    }
}

extern "C" void kernel_launch(void* const* d_in, const int* in_sizes, int n_in,
                              void* d_out, int out_size, void* d_ws, size_t ws_size,
                              hipStream_t stream) {
    (void)in_sizes; (void)n_in; (void)out_size; (void)ws_size;
    const float* x    = (const float*)d_in[0];
    const float* Jin  = (const float*)d_in[1];
    const float* Jrec = (const float*)d_in[2];
    const float* Jout = (const float*)d_in[3];
    const float* bias = (const float*)d_in[4];
    const float* h0   = (const float*)d_in[5];
    float* out = (float*)d_out;

    float* ws_out0 = (float*)d_ws;                            // 4096 f32
    unsigned short* ws_A = (unsigned short*)(ws_out0 + NB);   // 4096 bf16 (permuted)

    hipLaunchKernelGGL(setup_kernel, dim3(17), dim3(256), 0, stream,
                       Jin, Jrec, Jout, bias, h0, ws_out0, ws_A);
    hipLaunchKernelGGL(rnn_kernel, dim3(NB / 16), dim3(128), 0, stream,
                       x, h0, ws_out0, ws_A, out);
}